// Round 16
// baseline (194.309 us; speedup 1.0000x reference)
//
#include <hip/hip_runtime.h>
#include <math.h>

#define NN 100000
#define EE 3200000
#define FF 128
#define HH 6
#define CC 10
#define GG 512
#define NBUCK 196          // ceil(NN/512); bucket = dst >> 9
#define BCAP 20000         // per-bucket edge capacity (part array, real edges)
#define CCAP 21504         // per-bucket csr capacity (padded to 16-multiples per node)
#define NSUB 4             // sub-runs per bucket
#define SUBCAP 5000        // BCAP/NSUB
#define PTILE 16384        // 1024 threads x 16 edges
#define SUBIT 5            // 5*1024 = 5120 >= SUBCAP
#define GWIN 16            // per-block graph window for pooled reduction

typedef _Float16 half8 __attribute__((ext_vector_type(8)));

// ========== setup: sub-run cursors + graph bounds + gpool zero ==========
__global__ __launch_bounds__(256) void k_setup(const int* __restrict__ batch,
                                               int* __restrict__ gcur,
                                               int* __restrict__ bounds,
                                               float* __restrict__ gpool) {
    int i = blockIdx.x * 256 + threadIdx.x;
    if (i < NBUCK * NSUB) gcur[i] = (i >> 2) * BCAP + (i & 3) * SUBCAP;
    if (i <= GG) {
        int lo = 0, hi = NN;
        while (lo < hi) {
            int mid = (lo + hi) >> 1;
            if (batch[mid] < i) lo = mid + 1; else hi = mid;
        }
        bounds[i] = lo;
    }
    for (int j = i; j < GG * CC; j += 1024) gpool[j] = 0.f;
}

// ========== partition packed edges into bucket sub-runs (int4 edge loads) ==========
__global__ __launch_bounds__(1024) void k_partition(const int* __restrict__ src,
                                                    const int* __restrict__ dst,
                                                    int* __restrict__ gcur,
                                                    int* __restrict__ part) {
    __shared__ int lcnt[NBUCK], lbase[NBUCK];
    int t = threadIdx.x;
    int slot = blockIdx.x & (NSUB - 1);
    if (t < NBUCK) lcnt[t] = 0;
    __syncthreads();
    int base = blockIdx.x * PTILE;
    int d[16], s[16], r[16];
#pragma unroll
    for (int q = 0; q < 4; ++q) {
        int e0 = base + (q << 12) + (t << 2);
        if (e0 + 3 < EE) {
            int4 dv = *((const int4*)(dst + e0));
            int4 sv = *((const int4*)(src + e0));
            d[q * 4 + 0] = dv.x; d[q * 4 + 1] = dv.y; d[q * 4 + 2] = dv.z; d[q * 4 + 3] = dv.w;
            s[q * 4 + 0] = sv.x; s[q * 4 + 1] = sv.y; s[q * 4 + 2] = sv.z; s[q * 4 + 3] = sv.w;
        } else {
#pragma unroll
            for (int j = 0; j < 4; ++j) {
                int e = e0 + j;
                d[q * 4 + j] = (e < EE) ? dst[e] : -1;
                s[q * 4 + j] = (e < EE) ? src[e] : 0;
            }
        }
    }
#pragma unroll
    for (int k = 0; k < 16; ++k)
        if (d[k] >= 0) r[k] = atomicAdd(&lcnt[d[k] >> 9], 1);
    __syncthreads();
    if (t < NBUCK) lbase[t] = lcnt[t] ? atomicAdd(&gcur[t * NSUB + slot], lcnt[t]) : 0;
    __syncthreads();
#pragma unroll
    for (int k = 0; k < 16; ++k) {
        if (d[k] >= 0) {
            int bkt = d[k] >> 9;
            part[lbase[bkt] + r[k]] = (s[k] << 9) | (d[k] & 511);
        }
    }
}

// ========== per-bucket counting sort over 4 sub-runs, padded csr, int2 rowcnt ==========
__global__ __launch_bounds__(1024) void k_bucketfill(const int* __restrict__ gcur,
                                                     const int* __restrict__ part,
                                                     int* __restrict__ csr,
                                                     int2* __restrict__ rowcnt,
                                                     float* __restrict__ dinv) {
    __shared__ int cnt[512];
    __shared__ int wsum[16];
    int t = threadIdx.x, b = blockIdx.x;
    int nbase = b << 9;
    int ebase = b * BCAP;
    int cbase = b * CCAP;
    int rend0 = gcur[b * NSUB + 0], rend1 = gcur[b * NSUB + 1];
    int rend2 = gcur[b * NSUB + 2], rend3 = gcur[b * NSUB + 3];
    if (t < 512) cnt[t] = 0;
    __syncthreads();
    int p[NSUB * SUBIT], r[NSUB * SUBIT];
#pragma unroll
    for (int q = 0; q < NSUB; ++q) {
        int rbase = ebase + q * SUBCAP;
        int rend = (q == 0) ? rend0 : (q == 1) ? rend1 : (q == 2) ? rend2 : rend3;
#pragma unroll
        for (int it = 0; it < SUBIT; ++it) {
            int j = rbase + (it << 10) + t;
            p[q * SUBIT + it] = (j < rend) ? part[j] : -1;
        }
    }
#pragma unroll
    for (int it = 0; it < NSUB * SUBIT; ++it)
        if (p[it] >= 0) r[it] = atomicAdd(&cnt[p[it] & 511], 1);
    __syncthreads();
    int c = (t < 512) ? cnt[t] : 0;
    int pc = (c + 15) & ~15;          // padded count (16-multiple)
    int lane = t & 63, wv = t >> 6;
    int v = pc;
#pragma unroll
    for (int off = 1; off < 64; off <<= 1) {
        int u = __shfl_up(v, off, 64);
        if (lane >= off) v += u;
    }
    if (lane == 63) wsum[wv] = v;
    __syncthreads();
    int acc = 0;
    for (int k = 0; k < wv; ++k) acc += wsum[k];
    int excl = cbase + acc + v - pc;  // padded exclusive base
    if (t < 512) {
        int node = nbase + t;
        if (node < NN) {
            rowcnt[node] = make_int2(excl, c);
            dinv[node] = rsqrtf((float)c + 1.0f);
        }
        cnt[t] = excl;   // reuse as per-node base for scatter
    }
    __syncthreads();
#pragma unroll
    for (int it = 0; it < NSUB * SUBIT; ++it)
        if (p[it] >= 0) csr[cnt[p[it] & 511] + r[it]] = p[it] >> 9;
    // fill pad slots with sentinel node NN (zero hs row -> contributes 0)
    if (t < 512) {
        for (int k = c; k < pc; ++k) csr[excl + k] = NN;
    }
}

// ========== layer 1: hs = dinv * (x @ W1) -> half, 8-pad; 4 lanes per node ==========
__global__ __launch_bounds__(256) void k_xw1(const float* __restrict__ x,
                                             const float* __restrict__ W,
                                             const float* __restrict__ dinv,
                                             _Float16* __restrict__ hs) {
    __shared__ float sW[FF * HH];
    for (int i = threadIdx.x; i < FF * HH; i += 256) sW[i] = W[i];
    __syncthreads();
    int node = blockIdx.x * 64 + (threadIdx.x >> 2);
    int sub  = threadIdx.x & 3;
    if (blockIdx.x == 0 && threadIdx.x == 0) {   // sentinel zero row
        half8 z;
#pragma unroll
        for (int c = 0; c < 8; ++c) z[c] = (_Float16)0.f;
        *((half8*)(hs + (size_t)NN * 8)) = z;
    }
    if (node >= NN) return;
    const float4* xr = (const float4*)(x + (size_t)node * FF + sub * 32);
    float acc[HH];
#pragma unroll
    for (int c = 0; c < HH; ++c) acc[c] = 0.f;
#pragma unroll
    for (int q = 0; q < 8; ++q) {
        float4 v = xr[q];
        int k = sub * 32 + q * 4;
        const float* w0 = &sW[(k + 0) * HH];
        const float* w1 = &sW[(k + 1) * HH];
        const float* w2 = &sW[(k + 2) * HH];
        const float* w3 = &sW[(k + 3) * HH];
#pragma unroll
        for (int c = 0; c < HH; ++c)
            acc[c] += v.x * w0[c] + v.y * w1[c] + v.z * w2[c] + v.w * w3[c];
    }
#pragma unroll
    for (int c = 0; c < HH; ++c) {
        acc[c] += __shfl_xor(acc[c], 1, 64);
        acc[c] += __shfl_xor(acc[c], 2, 64);
    }
    if (sub == 0) {
        float di = dinv[node];
        half8 o;
#pragma unroll
        for (int c = 0; c < HH; ++c) o[c] = (_Float16)(di * acc[c]);
        o[6] = (_Float16)0.f; o[7] = (_Float16)0.f;
        *((half8*)(hs + (size_t)node * 8)) = o;
    }
}

// ===== fused gather + next mm, 4 lanes per node, int4 csr, int2 rowcnt, tail-free =====
template <int HON, int HPOH>
__global__ __launch_bounds__(256) void k_gf(const int2* __restrict__ rowcnt,
                                            const int* __restrict__ csr,
                                            const float* __restrict__ dinv,
                                            const _Float16* __restrict__ hs,
                                            const float* __restrict__ bias,
                                            const float* __restrict__ Wn,
                                            _Float16* __restrict__ outn) {
    __shared__ float sW[HH * HON];
    int node = blockIdx.x * 64 + (threadIdx.x >> 2);
    int sub  = threadIdx.x & 3;
    // issue the rowcnt load BEFORE the staging barrier so it overlaps the LDS wait
    int2 rc = make_int2(0, 0);
    if (node < NN) rc = rowcnt[node];
    if (threadIdx.x < HH * HON) sW[threadIdx.x] = Wn[threadIdx.x];
    __syncthreads();
    if (blockIdx.x == 0 && threadIdx.x == 0) {   // sentinel zero row for next layer
#pragma unroll
        for (int q = 0; q < HPOH / 8; ++q) {
            half8 z;
#pragma unroll
            for (int c = 0; c < 8; ++c) z[c] = (_Float16)0.f;
            *((half8*)(outn + (size_t)NN * HPOH + q * 8)) = z;
        }
    }
    if (node >= NN) return;
    int st = rc.x, cnt = rc.y;
    float a[HH];
    if (sub == 0) {
        half8 v = *((const half8*)(hs + (size_t)node * 8));
#pragma unroll
        for (int c = 0; c < HH; ++c) a[c] = (float)v[c];
    } else {
#pragma unroll
        for (int c = 0; c < HH; ++c) a[c] = 0.f;
    }
    int nfull = ((cnt + 15) & ~15) >> 4;
#pragma unroll 3
    for (int m = 0; m < nfull; ++m) {
        int4 s4 = *((const int4*)(csr + st + (m << 4) + (sub << 2)));
        half8 v0 = *((const half8*)(hs + (size_t)s4.x * 8));
        half8 v1 = *((const half8*)(hs + (size_t)s4.y * 8));
        half8 v2 = *((const half8*)(hs + (size_t)s4.z * 8));
        half8 v3 = *((const half8*)(hs + (size_t)s4.w * 8));
#pragma unroll
        for (int c = 0; c < HH; ++c)
            a[c] += ((float)v0[c] + (float)v1[c]) + ((float)v2[c] + (float)v3[c]);
    }
#pragma unroll
    for (int c = 0; c < HH; ++c) {
        a[c] += __shfl_xor(a[c], 1, 64);
        a[c] += __shfl_xor(a[c], 2, 64);
    }
    if (sub == 0) {
        float di = dinv[node];
        float h[HH];
#pragma unroll
        for (int c = 0; c < HH; ++c) h[c] = fmaxf(di * a[c] + bias[c], 0.f);
        half8 o[HPOH / 8];
#pragma unroll
        for (int c = 0; c < HPOH; ++c) {
            float s = 0.f;
            if (c < HON) {
#pragma unroll
                for (int k = 0; k < HH; ++k) s += h[k] * sW[k * HON + c];
                o[c / 8][c % 8] = (_Float16)(di * s);
            } else {
                o[c / 8][c % 8] = (_Float16)0.f;
            }
        }
        half8* op = (half8*)(outn + (size_t)node * HPOH);
#pragma unroll
        for (int q = 0; q < HPOH / 8; ++q) op[q] = o[q];
    }
}

// ===== last gather (int4 csr, int2 rowcnt, tail-free) + block-reduced pool =====
__global__ __launch_bounds__(256) void k_glast(const int2* __restrict__ rowcnt,
                                               const int* __restrict__ csr,
                                               const float* __restrict__ dinv,
                                               const _Float16* __restrict__ hs,
                                               const float* __restrict__ bias,
                                               const int* __restrict__ batch,
                                               float* __restrict__ gpool) {
    __shared__ float gacc[GWIN * CC];
    int t = threadIdx.x;
    int node = blockIdx.x * 64 + (t >> 2);
    int sub  = t & 3;
    bool live = (node < NN);
    int2 rc = make_int2(0, 0);
    if (live) rc = rowcnt[node];
    for (int i = t; i < GWIN * CC; i += 256) gacc[i] = 0.f;
    int gmin = batch[blockIdx.x * 64];
    __syncthreads();
    int st = rc.x, cnt = rc.y;
    float a[CC];
#pragma unroll
    for (int c = 0; c < CC; ++c) a[c] = 0.f;
    if (live && sub == 0) {
        const half8* p = (const half8*)(hs + (size_t)node * 16);
        half8 v0 = p[0], v1 = p[1];
#pragma unroll
        for (int c = 0; c < 8; ++c) a[c] = (float)v0[c];
        a[8] = (float)v1[0]; a[9] = (float)v1[1];
    }
    int nfull = ((cnt + 15) & ~15) >> 4;
#pragma unroll 3
    for (int m = 0; m < nfull; ++m) {
        int4 s4 = *((const int4*)(csr + st + (m << 4) + (sub << 2)));
        const half8* p0 = (const half8*)(hs + (size_t)s4.x * 16);
        const half8* p1 = (const half8*)(hs + (size_t)s4.y * 16);
        const half8* p2 = (const half8*)(hs + (size_t)s4.z * 16);
        const half8* p3 = (const half8*)(hs + (size_t)s4.w * 16);
        half8 x0 = p0[0], y0 = p0[1], x1 = p1[0], y1 = p1[1];
        half8 x2 = p2[0], y2 = p2[1], x3 = p3[0], y3 = p3[1];
#pragma unroll
        for (int c = 0; c < 8; ++c)
            a[c] += ((float)x0[c] + (float)x1[c]) + ((float)x2[c] + (float)x3[c]);
        a[8] += ((float)y0[0] + (float)y1[0]) + ((float)y2[0] + (float)y3[0]);
        a[9] += ((float)y0[1] + (float)y1[1]) + ((float)y2[1] + (float)y3[1]);
    }
#pragma unroll
    for (int c = 0; c < CC; ++c) {
        a[c] += __shfl_xor(a[c], 1, 64);
        a[c] += __shfl_xor(a[c], 2, 64);
    }
    if (live && sub == 0) {
        float di = dinv[node];
        int g = batch[node];
        int off = g - gmin;
        if (off < GWIN) {
#pragma unroll
            for (int c = 0; c < CC; ++c) {
                float rv = fmaxf(di * a[c] + bias[c], 0.f);
                if (rv != 0.f) atomicAdd(&gacc[off * CC + c], rv);
            }
        } else {  // pathological tiny-graph run; correctness fallback
#pragma unroll
            for (int c = 0; c < CC; ++c) {
                float rv = fmaxf(di * a[c] + bias[c], 0.f);
                if (rv != 0.f) atomicAdd(&gpool[(size_t)g * CC + c], rv);
            }
        }
    }
    __syncthreads();
    for (int i = t; i < GWIN * CC; i += 256) {
        float v = gacc[i];
        int g = gmin + i / CC;
        if (v != 0.f && g < GG) atomicAdd(&gpool[(size_t)g * CC + i % CC], v);
    }
}

// ========== finalize: mean + log_softmax, one thread per graph ==========
__global__ __launch_bounds__(256) void k_poolfin(const float* __restrict__ gpool,
                                                 const int* __restrict__ bounds,
                                                 float* __restrict__ out) {
    int g = blockIdx.x * 256 + threadIdx.x;
    if (g >= GG) return;
    float cntf = fmaxf((float)(bounds[g + 1] - bounds[g]), 1.0f);
    float tot[CC];
    float m = -1e30f;
#pragma unroll
    for (int c = 0; c < CC; ++c) {
        tot[c] = gpool[(size_t)g * CC + c] / cntf;
        m = fmaxf(m, tot[c]);
    }
    float ss = 0.f;
#pragma unroll
    for (int c = 0; c < CC; ++c) ss += expf(tot[c] - m);
    float lse = logf(ss) + m;
#pragma unroll
    for (int c = 0; c < CC; ++c) out[(size_t)g * CC + c] = tot[c] - lse;
}

extern "C" void kernel_launch(void* const* d_in, const int* in_sizes, int n_in,
                              void* d_out, int out_size, void* d_ws, size_t ws_size,
                              hipStream_t stream) {
    const float* x     = (const float*)d_in[0];
    const int*   ei    = (const int*)d_in[1];
    const int*   batch = (const int*)d_in[2];
    const float* W1 = (const float*)d_in[3];
    const float* b1 = (const float*)d_in[4];
    const float* W2 = (const float*)d_in[5];
    const float* b2 = (const float*)d_in[6];
    const float* W3 = (const float*)d_in[7];
    const float* b3 = (const float*)d_in[8];
    const float* W4 = (const float*)d_in[9];
    const float* b4 = (const float*)d_in[10];
    const float* Wf = (const float*)d_in[11];
    const float* bf = (const float*)d_in[12];
    float* out = (float*)d_out;

    const int* src = ei;
    const int* dst = ei + EE;

    // -------- workspace layout (4B units) --------
    int*   iw     = (int*)d_ws;
    int*   csr    = iw;                        // [4,214,784] padded, bucket-strided
    int2*  rowcnt = (int2*)(csr + 4214784);    // [100,352] (int2 -> 200,704 ints)
    float* dinv   = (float*)(rowcnt + 100352); // [100,352]
    int*   gcur   = (int*)(dinv + 100352);     // [784 -> pad 1024]
    int*   bounds = gcur + 1024;               // [640]
    float* gpool  = (float*)(bounds + 640);    // [5,376]
    int*   part   = (int*)(gpool + 5376);      // [3,920,000], overlaid after bucketfill:
    _Float16* hsA = (_Float16*)part;           //   [1,605,632 halves]
    _Float16* hsB = hsA + 1605632;             //   [1,605,632 halves]

    const int TB = (EE + PTILE - 1) / PTILE;   // 196
    const int GB = (NN + 63) / 64;             // 1563 (4 lanes per node)

    // -------- CSR build --------
    k_setup<<<4, 256, 0, stream>>>(batch, gcur, bounds, gpool);
    k_partition<<<TB, 1024, 0, stream>>>(src, dst, gcur, part);
    k_bucketfill<<<NBUCK, 1024, 0, stream>>>(gcur, part, csr, rowcnt, dinv);

    // -------- layers --------
    k_xw1<<<GB, 256, 0, stream>>>(x, W1, dinv, hsA);                                       // hs1
    k_gf<HH, 8><<<GB, 256, 0, stream>>>(rowcnt, csr, dinv, hsA, b1, W2, hsB);              // hs2
    k_gf<HH, 8><<<GB, 256, 0, stream>>>(rowcnt, csr, dinv, hsB, b2, W3, hsA);              // hs3
    k_gf<HH, 8><<<GB, 256, 0, stream>>>(rowcnt, csr, dinv, hsA, b3, W4, hsB);              // hs4
    k_gf<CC, 16><<<GB, 256, 0, stream>>>(rowcnt, csr, dinv, hsB, b4, Wf, hsA);             // hs5 (16-pad)
    k_glast<<<GB, 256, 0, stream>>>(rowcnt, csr, dinv, hsA, bf, batch, gpool);             // + pool accum

    // -------- finalize --------
    k_poolfin<<<2, 256, 0, stream>>>(gpool, bounds, out);
}

// Round 17
// 190.816 us; speedup vs baseline: 1.0183x; 1.0183x over previous
//
#include <hip/hip_runtime.h>
#include <math.h>

#define NN 100000
#define EE 3200000
#define FF 128
#define HH 6
#define CC 10
#define GG 512
#define NBUCK 196          // ceil(NN/512); bucket = dst >> 9
#define BCAP 20000         // per-bucket edge capacity (part array, real edges)
#define CCAP 21504         // per-bucket csr capacity (padded to 16-multiples per node)
#define NSUB 4             // sub-runs per bucket
#define SUBCAP 5000        // BCAP/NSUB
#define PTILE 16384        // 1024 threads x 16 edges
#define SUBIT 5            // 5*1024 = 5120 >= SUBCAP
#define GWIN 16            // per-block graph window for pooled reduction

typedef _Float16 half8 __attribute__((ext_vector_type(8)));

// ========== setup: sub-run cursors + graph bounds + gpool zero ==========
__global__ __launch_bounds__(256) void k_setup(const int* __restrict__ batch,
                                               int* __restrict__ gcur,
                                               int* __restrict__ bounds,
                                               float* __restrict__ gpool) {
    int i = blockIdx.x * 256 + threadIdx.x;
    if (i < NBUCK * NSUB) gcur[i] = (i >> 2) * BCAP + (i & 3) * SUBCAP;
    if (i <= GG) {
        int lo = 0, hi = NN;
        while (lo < hi) {
            int mid = (lo + hi) >> 1;
            if (batch[mid] < i) lo = mid + 1; else hi = mid;
        }
        bounds[i] = lo;
    }
    for (int j = i; j < GG * CC; j += 1024) gpool[j] = 0.f;
}

// ========== partition packed edges into bucket sub-runs (int4 edge loads) ==========
__global__ __launch_bounds__(1024) void k_partition(const int* __restrict__ src,
                                                    const int* __restrict__ dst,
                                                    int* __restrict__ gcur,
                                                    int* __restrict__ part) {
    __shared__ int lcnt[NBUCK], lbase[NBUCK];
    int t = threadIdx.x;
    int slot = blockIdx.x & (NSUB - 1);
    if (t < NBUCK) lcnt[t] = 0;
    __syncthreads();
    int base = blockIdx.x * PTILE;
    int d[16], s[16], r[16];
#pragma unroll
    for (int q = 0; q < 4; ++q) {
        int e0 = base + (q << 12) + (t << 2);
        if (e0 + 3 < EE) {
            int4 dv = *((const int4*)(dst + e0));
            int4 sv = *((const int4*)(src + e0));
            d[q * 4 + 0] = dv.x; d[q * 4 + 1] = dv.y; d[q * 4 + 2] = dv.z; d[q * 4 + 3] = dv.w;
            s[q * 4 + 0] = sv.x; s[q * 4 + 1] = sv.y; s[q * 4 + 2] = sv.z; s[q * 4 + 3] = sv.w;
        } else {
#pragma unroll
            for (int j = 0; j < 4; ++j) {
                int e = e0 + j;
                d[q * 4 + j] = (e < EE) ? dst[e] : -1;
                s[q * 4 + j] = (e < EE) ? src[e] : 0;
            }
        }
    }
#pragma unroll
    for (int k = 0; k < 16; ++k)
        if (d[k] >= 0) r[k] = atomicAdd(&lcnt[d[k] >> 9], 1);
    __syncthreads();
    if (t < NBUCK) lbase[t] = lcnt[t] ? atomicAdd(&gcur[t * NSUB + slot], lcnt[t]) : 0;
    __syncthreads();
#pragma unroll
    for (int k = 0; k < 16; ++k) {
        if (d[k] >= 0) {
            int bkt = d[k] >> 9;
            part[lbase[bkt] + r[k]] = (s[k] << 9) | (d[k] & 511);
        }
    }
}

// ========== per-bucket counting sort over 4 sub-runs, padded csr, int2 rowcnt ==========
__global__ __launch_bounds__(1024) void k_bucketfill(const int* __restrict__ gcur,
                                                     const int* __restrict__ part,
                                                     int* __restrict__ csr,
                                                     int2* __restrict__ rowcnt,
                                                     float* __restrict__ dinv) {
    __shared__ int cnt[512];
    __shared__ int wsum[16];
    int t = threadIdx.x, b = blockIdx.x;
    int nbase = b << 9;
    int ebase = b * BCAP;
    int cbase = b * CCAP;
    int rend0 = gcur[b * NSUB + 0], rend1 = gcur[b * NSUB + 1];
    int rend2 = gcur[b * NSUB + 2], rend3 = gcur[b * NSUB + 3];
    if (t < 512) cnt[t] = 0;
    __syncthreads();
    int p[NSUB * SUBIT], r[NSUB * SUBIT];
#pragma unroll
    for (int q = 0; q < NSUB; ++q) {
        int rbase = ebase + q * SUBCAP;
        int rend = (q == 0) ? rend0 : (q == 1) ? rend1 : (q == 2) ? rend2 : rend3;
#pragma unroll
        for (int it = 0; it < SUBIT; ++it) {
            int j = rbase + (it << 10) + t;
            p[q * SUBIT + it] = (j < rend) ? part[j] : -1;
        }
    }
#pragma unroll
    for (int it = 0; it < NSUB * SUBIT; ++it)
        if (p[it] >= 0) r[it] = atomicAdd(&cnt[p[it] & 511], 1);
    __syncthreads();
    int c = (t < 512) ? cnt[t] : 0;
    int pc = (c + 15) & ~15;          // padded count (16-multiple)
    int lane = t & 63, wv = t >> 6;
    int v = pc;
#pragma unroll
    for (int off = 1; off < 64; off <<= 1) {
        int u = __shfl_up(v, off, 64);
        if (lane >= off) v += u;
    }
    if (lane == 63) wsum[wv] = v;
    __syncthreads();
    int acc = 0;
    for (int k = 0; k < wv; ++k) acc += wsum[k];
    int excl = cbase + acc + v - pc;  // padded exclusive base
    if (t < 512) {
        int node = nbase + t;
        if (node < NN) {
            rowcnt[node] = make_int2(excl, c);
            dinv[node] = rsqrtf((float)c + 1.0f);
        }
        cnt[t] = excl;   // reuse as per-node base for scatter
    }
    __syncthreads();
#pragma unroll
    for (int it = 0; it < NSUB * SUBIT; ++it)
        if (p[it] >= 0) csr[cnt[p[it] & 511] + r[it]] = p[it] >> 9;
    // fill pad slots with sentinel node NN (zero hs row -> contributes 0)
    if (t < 512) {
        for (int k = c; k < pc; ++k) csr[excl + k] = NN;
    }
}

// ========== layer 1: hs = dinv * (x @ W1) -> half, 8-pad; 4 lanes per node ==========
__global__ __launch_bounds__(256) void k_xw1(const float* __restrict__ x,
                                             const float* __restrict__ W,
                                             const float* __restrict__ dinv,
                                             _Float16* __restrict__ hs) {
    __shared__ float sW[FF * HH];
    for (int i = threadIdx.x; i < FF * HH; i += 256) sW[i] = W[i];
    __syncthreads();
    int node = blockIdx.x * 64 + (threadIdx.x >> 2);
    int sub  = threadIdx.x & 3;
    if (blockIdx.x == 0 && threadIdx.x == 0) {   // sentinel zero row
        half8 z;
#pragma unroll
        for (int c = 0; c < 8; ++c) z[c] = (_Float16)0.f;
        *((half8*)(hs + (size_t)NN * 8)) = z;
    }
    if (node >= NN) return;
    const float4* xr = (const float4*)(x + (size_t)node * FF + sub * 32);
    float acc[HH];
#pragma unroll
    for (int c = 0; c < HH; ++c) acc[c] = 0.f;
#pragma unroll
    for (int q = 0; q < 8; ++q) {
        float4 v = xr[q];
        int k = sub * 32 + q * 4;
        const float* w0 = &sW[(k + 0) * HH];
        const float* w1 = &sW[(k + 1) * HH];
        const float* w2 = &sW[(k + 2) * HH];
        const float* w3 = &sW[(k + 3) * HH];
#pragma unroll
        for (int c = 0; c < HH; ++c)
            acc[c] += v.x * w0[c] + v.y * w1[c] + v.z * w2[c] + v.w * w3[c];
    }
#pragma unroll
    for (int c = 0; c < HH; ++c) {
        acc[c] += __shfl_xor(acc[c], 1, 64);
        acc[c] += __shfl_xor(acc[c], 2, 64);
    }
    if (sub == 0) {
        float di = dinv[node];
        half8 o;
#pragma unroll
        for (int c = 0; c < HH; ++c) o[c] = (_Float16)(di * acc[c]);
        o[6] = (_Float16)0.f; o[7] = (_Float16)0.f;
        *((half8*)(hs + (size_t)node * 8)) = o;
    }
}

// ===== fused gather + next mm, 8 lanes per node (32 nodes/block), int2 csr =====
template <int HON, int HPOH>
__global__ __launch_bounds__(256) void k_gf(const int2* __restrict__ rowcnt,
                                            const int* __restrict__ csr,
                                            const float* __restrict__ dinv,
                                            const _Float16* __restrict__ hs,
                                            const float* __restrict__ bias,
                                            const float* __restrict__ Wn,
                                            _Float16* __restrict__ outn) {
    __shared__ float sW[HH * HON];
    int node = blockIdx.x * 32 + (threadIdx.x >> 3);
    int sub  = threadIdx.x & 7;
    int2 rc = make_int2(0, 0);
    if (node < NN) rc = rowcnt[node];
    if (threadIdx.x < HH * HON) sW[threadIdx.x] = Wn[threadIdx.x];
    __syncthreads();
    if (blockIdx.x == 0 && threadIdx.x == 0) {   // sentinel zero row for next layer
#pragma unroll
        for (int q = 0; q < HPOH / 8; ++q) {
            half8 z;
#pragma unroll
            for (int c = 0; c < 8; ++c) z[c] = (_Float16)0.f;
            *((half8*)(outn + (size_t)NN * HPOH + q * 8)) = z;
        }
    }
    if (node >= NN) return;
    int st = rc.x, cnt = rc.y;
    float a[HH];
    if (sub == 0) {
        half8 v = *((const half8*)(hs + (size_t)node * 8));
#pragma unroll
        for (int c = 0; c < HH; ++c) a[c] = (float)v[c];
    } else {
#pragma unroll
        for (int c = 0; c < HH; ++c) a[c] = 0.f;
    }
    int nfull = ((cnt + 15) & ~15) >> 4;
#pragma unroll 3
    for (int m = 0; m < nfull; ++m) {
        int2 s2 = *((const int2*)(csr + st + (m << 4) + (sub << 1)));
        half8 v0 = *((const half8*)(hs + (size_t)s2.x * 8));
        half8 v1 = *((const half8*)(hs + (size_t)s2.y * 8));
#pragma unroll
        for (int c = 0; c < HH; ++c)
            a[c] += (float)v0[c] + (float)v1[c];
    }
#pragma unroll
    for (int c = 0; c < HH; ++c) {
        a[c] += __shfl_xor(a[c], 1, 64);
        a[c] += __shfl_xor(a[c], 2, 64);
        a[c] += __shfl_xor(a[c], 4, 64);
    }
    if (sub == 0) {
        float di = dinv[node];
        float h[HH];
#pragma unroll
        for (int c = 0; c < HH; ++c) h[c] = fmaxf(di * a[c] + bias[c], 0.f);
        half8 o[HPOH / 8];
#pragma unroll
        for (int c = 0; c < HPOH; ++c) {
            float s = 0.f;
            if (c < HON) {
#pragma unroll
                for (int k = 0; k < HH; ++k) s += h[k] * sW[k * HON + c];
                o[c / 8][c % 8] = (_Float16)(di * s);
            } else {
                o[c / 8][c % 8] = (_Float16)0.f;
            }
        }
        half8* op = (half8*)(outn + (size_t)node * HPOH);
#pragma unroll
        for (int q = 0; q < HPOH / 8; ++q) op[q] = o[q];
    }
}

// ===== last gather, 8 lanes per node, int2 csr + block-reduced pool =====
__global__ __launch_bounds__(256) void k_glast(const int2* __restrict__ rowcnt,
                                               const int* __restrict__ csr,
                                               const float* __restrict__ dinv,
                                               const _Float16* __restrict__ hs,
                                               const float* __restrict__ bias,
                                               const int* __restrict__ batch,
                                               float* __restrict__ gpool) {
    __shared__ float gacc[GWIN * CC];
    int t = threadIdx.x;
    int node = blockIdx.x * 32 + (t >> 3);
    int sub  = t & 7;
    bool live = (node < NN);
    int2 rc = make_int2(0, 0);
    if (live) rc = rowcnt[node];
    for (int i = t; i < GWIN * CC; i += 256) gacc[i] = 0.f;
    int gmin = batch[blockIdx.x * 32];
    __syncthreads();
    int st = rc.x, cnt = rc.y;
    float a[CC];
#pragma unroll
    for (int c = 0; c < CC; ++c) a[c] = 0.f;
    if (live && sub == 0) {
        const half8* p = (const half8*)(hs + (size_t)node * 16);
        half8 v0 = p[0], v1 = p[1];
#pragma unroll
        for (int c = 0; c < 8; ++c) a[c] = (float)v0[c];
        a[8] = (float)v1[0]; a[9] = (float)v1[1];
    }
    int nfull = ((cnt + 15) & ~15) >> 4;
#pragma unroll 3
    for (int m = 0; m < nfull; ++m) {
        int2 s2 = *((const int2*)(csr + st + (m << 4) + (sub << 1)));
        const half8* p0 = (const half8*)(hs + (size_t)s2.x * 16);
        const half8* p1 = (const half8*)(hs + (size_t)s2.y * 16);
        half8 x0 = p0[0], y0 = p0[1], x1 = p1[0], y1 = p1[1];
#pragma unroll
        for (int c = 0; c < 8; ++c)
            a[c] += (float)x0[c] + (float)x1[c];
        a[8] += (float)y0[0] + (float)y1[0];
        a[9] += (float)y0[1] + (float)y1[1];
    }
#pragma unroll
    for (int c = 0; c < CC; ++c) {
        a[c] += __shfl_xor(a[c], 1, 64);
        a[c] += __shfl_xor(a[c], 2, 64);
        a[c] += __shfl_xor(a[c], 4, 64);
    }
    if (live && sub == 0) {
        float di = dinv[node];
        int g = batch[node];
        int off = g - gmin;
        if (off < GWIN) {
#pragma unroll
            for (int c = 0; c < CC; ++c) {
                float rv = fmaxf(di * a[c] + bias[c], 0.f);
                if (rv != 0.f) atomicAdd(&gacc[off * CC + c], rv);
            }
        } else {  // pathological tiny-graph run; correctness fallback
#pragma unroll
            for (int c = 0; c < CC; ++c) {
                float rv = fmaxf(di * a[c] + bias[c], 0.f);
                if (rv != 0.f) atomicAdd(&gpool[(size_t)g * CC + c], rv);
            }
        }
    }
    __syncthreads();
    for (int i = t; i < GWIN * CC; i += 256) {
        float v = gacc[i];
        int g = gmin + i / CC;
        if (v != 0.f && g < GG) atomicAdd(&gpool[(size_t)g * CC + i % CC], v);
    }
}

// ========== finalize: mean + log_softmax, one thread per graph ==========
__global__ __launch_bounds__(256) void k_poolfin(const float* __restrict__ gpool,
                                                 const int* __restrict__ bounds,
                                                 float* __restrict__ out) {
    int g = blockIdx.x * 256 + threadIdx.x;
    if (g >= GG) return;
    float cntf = fmaxf((float)(bounds[g + 1] - bounds[g]), 1.0f);
    float tot[CC];
    float m = -1e30f;
#pragma unroll
    for (int c = 0; c < CC; ++c) {
        tot[c] = gpool[(size_t)g * CC + c] / cntf;
        m = fmaxf(m, tot[c]);
    }
    float ss = 0.f;
#pragma unroll
    for (int c = 0; c < CC; ++c) ss += expf(tot[c] - m);
    float lse = logf(ss) + m;
#pragma unroll
    for (int c = 0; c < CC; ++c) out[(size_t)g * CC + c] = tot[c] - lse;
}

extern "C" void kernel_launch(void* const* d_in, const int* in_sizes, int n_in,
                              void* d_out, int out_size, void* d_ws, size_t ws_size,
                              hipStream_t stream) {
    const float* x     = (const float*)d_in[0];
    const int*   ei    = (const int*)d_in[1];
    const int*   batch = (const int*)d_in[2];
    const float* W1 = (const float*)d_in[3];
    const float* b1 = (const float*)d_in[4];
    const float* W2 = (const float*)d_in[5];
    const float* b2 = (const float*)d_in[6];
    const float* W3 = (const float*)d_in[7];
    const float* b3 = (const float*)d_in[8];
    const float* W4 = (const float*)d_in[9];
    const float* b4 = (const float*)d_in[10];
    const float* Wf = (const float*)d_in[11];
    const float* bf = (const float*)d_in[12];
    float* out = (float*)d_out;

    const int* src = ei;
    const int* dst = ei + EE;

    // -------- workspace layout (4B units) --------
    int*   iw     = (int*)d_ws;
    int*   csr    = iw;                        // [4,214,784] padded, bucket-strided
    int2*  rowcnt = (int2*)(csr + 4214784);    // [100,352] (int2 -> 200,704 ints)
    float* dinv   = (float*)(rowcnt + 100352); // [100,352]
    int*   gcur   = (int*)(dinv + 100352);     // [784 -> pad 1024]
    int*   bounds = gcur + 1024;               // [640]
    float* gpool  = (float*)(bounds + 640);    // [5,376]
    int*   part   = (int*)(gpool + 5376);      // [3,920,000], overlaid after bucketfill:
    _Float16* hsA = (_Float16*)part;           //   [1,605,632 halves]
    _Float16* hsB = hsA + 1605632;             //   [1,605,632 halves]

    const int TB  = (EE + PTILE - 1) / PTILE;  // 196
    const int GB  = (NN + 63) / 64;            // 1563 (4 lanes/node, xw1)
    const int GB8 = (NN + 31) / 32;            // 3125 (8 lanes/node, gathers)

    // -------- CSR build --------
    k_setup<<<4, 256, 0, stream>>>(batch, gcur, bounds, gpool);
    k_partition<<<TB, 1024, 0, stream>>>(src, dst, gcur, part);
    k_bucketfill<<<NBUCK, 1024, 0, stream>>>(gcur, part, csr, rowcnt, dinv);

    // -------- layers --------
    k_xw1<<<GB, 256, 0, stream>>>(x, W1, dinv, hsA);                                       // hs1
    k_gf<HH, 8><<<GB8, 256, 0, stream>>>(rowcnt, csr, dinv, hsA, b1, W2, hsB);             // hs2
    k_gf<HH, 8><<<GB8, 256, 0, stream>>>(rowcnt, csr, dinv, hsB, b2, W3, hsA);             // hs3
    k_gf<HH, 8><<<GB8, 256, 0, stream>>>(rowcnt, csr, dinv, hsA, b3, W4, hsB);             // hs4
    k_gf<CC, 16><<<GB8, 256, 0, stream>>>(rowcnt, csr, dinv, hsB, b4, Wf, hsA);            // hs5 (16-pad)
    k_glast<<<GB8, 256, 0, stream>>>(rowcnt, csr, dinv, hsA, bf, batch, gpool);            // + pool accum

    // -------- finalize --------
    k_poolfin<<<2, 256, 0, stream>>>(gpool, bounds, out);
}